// Round 1
// baseline (132.552 us; speedup 1.0000x reference)
//
#include <hip/hip_runtime.h>
#include <math.h>

#define NB 4096
#define NF 2048
#define NM 14
#define NC 100
#define NK 16384

__device__ __forceinline__ float softplus_f(float v) {
    return fmaxf(v, 0.f) + log1pf(__expf(-fabsf(v)));
}

// K1: le[b][j] += x[b]·alpha[j]  (alpha_0 added in K3)
// grid 512: blockIdx = (rowgroup<<1)|half ; 16 rows/block, 4 rows/wave, f-split x2
extern "C" __global__ void __launch_bounds__(256) k1_le(
        const float* __restrict__ x, const float* __restrict__ alpha,
        float* __restrict__ le_out) {
    const int tid = threadIdx.x;
    const int wave = tid >> 6, lane = tid & 63;
    const int grp = blockIdx.x >> 1;
    const int half = blockIdx.x & 1;
    const int row0 = grp * 16 + wave * 4;
    const float4* __restrict__ x4 = (const float4*)x;
    const float4* __restrict__ a4 = (const float4*)alpha;
    float acc[4][NM];
#pragma unroll
    for (int r = 0; r < 4; ++r)
#pragma unroll
        for (int j = 0; j < NM; ++j) acc[r][j] = 0.f;
#pragma unroll 1
    for (int cc = 0; cc < 4; ++cc) {
        const int f4i = half * 256 + cc * 64 + lane;
        float4 av[NM];
#pragma unroll
        for (int j = 0; j < NM; ++j) av[j] = a4[j * 512 + f4i];
#pragma unroll
        for (int r = 0; r < 4; ++r) {
            const float4 xv = x4[(row0 + r) * 512 + f4i];
#pragma unroll
            for (int j = 0; j < NM; ++j) {
                acc[r][j] = fmaf(xv.x, av[j].x, acc[r][j]);
                acc[r][j] = fmaf(xv.y, av[j].y, acc[r][j]);
                acc[r][j] = fmaf(xv.z, av[j].z, acc[r][j]);
                acc[r][j] = fmaf(xv.w, av[j].w, acc[r][j]);
            }
        }
    }
#pragma unroll
    for (int m = 1; m < 64; m <<= 1) {
#pragma unroll
        for (int r = 0; r < 4; ++r)
#pragma unroll
            for (int j = 0; j < NM; ++j)
                acc[r][j] += __shfl_xor(acc[r][j], m, 64);
    }
    if (lane == 0) {
        for (int r = 0; r < 4; ++r)
            for (int j = 0; j < NM; ++j)
                atomicAdd(&le_out[(row0 + r) * NM + j], acc[r][j]);
    }
}

// K2: SL[k] = (1/S_k, log S_k), S_k = sum_c exp(beta0_c + beta_c·(2cb_k-1))
// grid 256 blocks: 64 k each, 4 class-quarters per k. |lp| <= ~13 so no max-sub needed.
extern "C" __global__ void __launch_bounds__(256) k2_sl(
        const float* __restrict__ beta, const float* __restrict__ beta0,
        float2* __restrict__ SL) {
    __shared__ float b2[NC * NM];
    __shared__ float base_s[NC];
    __shared__ float Sp[4][64];
    const int tid = threadIdx.x;
    for (int i = tid; i < NC * NM; i += 256) b2[i] = 2.f * beta[i];
    if (tid < NC) {
        float s = beta0[tid];
        for (int j = 0; j < NM; ++j) s -= beta[tid * NM + j];
        base_s[tid] = s;
    }
    __syncthreads();
    const int kl = tid & 63, q = tid >> 6;
    const int k = blockIdx.x * 64 + kl;
    float bits[NM];
#pragma unroll
    for (int j = 0; j < NM; ++j) bits[j] = (float)((k >> (13 - j)) & 1);
    float S = 0.f;
    for (int c = q * 25; c < q * 25 + 25; ++c) {
        float d = base_s[c];
#pragma unroll
        for (int j = 0; j < NM; ++j) d = fmaf(bits[j], b2[c * NM + j], d);
        S += __expf(d);
    }
    Sp[q][kl] = S;
    __syncthreads();
    if (tid < 64) {
        const float Sf = Sp[0][tid] + Sp[1][tid] + Sp[2][tid] + Sp[3][tid];
        SL[blockIdx.x * 64 + tid] = make_float2(1.f / Sf, __logf(Sf));
    }
}

// K3: per row b: U = sum_k exp(g-stab), V = sum_k exp(g-stab)*(g-stab)
//     f_b = cs_b + V/U,  cs_b = beta0_y - sum beta_y - spsum + stab
// grid 512 blocks x 256 thr, 8 rows/block; k = i*256 + tid, i=0..63.
extern "C" __global__ void __launch_bounds__(256) k3_main(
        const float* __restrict__ le, const float* __restrict__ alpha0,
        const int* __restrict__ y, const float* __restrict__ beta,
        const float* __restrict__ beta0, const float2* __restrict__ SL,
        float* __restrict__ out) {
    __shared__ float t_s[8][16];
    __shared__ float sp_s[8][16];
    __shared__ float cs_s[8];
    __shared__ float Alds[128][8];   // Ahi' = Ahi - UBhi (per h, per row)
    __shared__ float Elds[128][8];   // exp(Ahi')
    __shared__ float red[4][16];
    const int tid = threadIdx.x;
    const int b0 = blockIdx.x * 8;

    if (tid < 128) {
        const int r = tid >> 4, j = tid & 15;
        if (j < NM) {
            const int yv = y[b0 + r];
            const float lv = le[(b0 + r) * NM + j] + alpha0[j];
            t_s[r][j] = lv + 2.f * beta[yv * NM + j];
            sp_s[r][j] = softplus_f(lv);
        }
    }
    __syncthreads();
    if (tid < 8) {
        const int yv = y[b0 + tid];
        float cs = beta0[yv];
        for (int j = 0; j < NM; ++j) {
            cs -= beta[yv * NM + j];
            cs += fmaxf(t_s[tid][j], 0.f) - sp_s[tid][j];  // stab - spsum
        }
        cs_s[tid] = cs;
    }
    // fill Ahi tables: 1024 entries = 128 h x 8 rows
#pragma unroll
    for (int e = 0; e < 4; ++e) {
        const int idx = tid + 256 * e;
        const int r = idx & 7, h = idx >> 3;
        float A = 0.f, ub = 0.f;
#pragma unroll
        for (int j = 0; j < 7; ++j) {
            const float tv = t_s[r][j];
            A += ((h >> (6 - j)) & 1) ? tv : 0.f;
            ub += fmaxf(tv, 0.f);
        }
        const float Ap = A - ub;
        Alds[h][r] = Ap;
        Elds[h][r] = __expf(Ap);
    }
    // per-thread Alo' and exp(Alo') per row (l = k & 127 = tid & 127)
    const int l = tid & 127;
    float eb[8], aterm[8];
#pragma unroll
    for (int r = 0; r < 8; ++r) {
        float A = 0.f, ub = 0.f;
#pragma unroll
        for (int j = 7; j < NM; ++j) {
            const float tv = t_s[r][j];
            A += ((l >> (13 - j)) & 1) ? tv : 0.f;
            ub += fmaxf(tv, 0.f);
        }
        aterm[r] = A - ub;
        eb[r] = __expf(A - ub);
    }
    __syncthreads();

    float U[8], V[8];
#pragma unroll
    for (int r = 0; r < 8; ++r) { U[r] = 0.f; V[r] = 0.f; }
    const int c = tid >> 7;   // wave-uniform
#pragma unroll 4
    for (int i = 0; i < 64; ++i) {
        const float2 sl = SL[i * 256 + tid];          // (1/S, logS) coalesced
        const int h = 2 * i + c;
        const float4 Aa = *(const float4*)&Alds[h][0];
        const float4 Ab = *(const float4*)&Alds[h][4];
        const float4 Ea = *(const float4*)&Elds[h][0];
        const float4 Eb = *(const float4*)&Elds[h][4];
        const float Ar[8] = {Aa.x, Aa.y, Aa.z, Aa.w, Ab.x, Ab.y, Ab.z, Ab.w};
        const float Er[8] = {Ea.x, Ea.y, Ea.z, Ea.w, Eb.x, Eb.y, Eb.z, Eb.w};
#pragma unroll
        for (int r = 0; r < 8; ++r) {
            const float rest = Er[r] * sl.x;          // exp(Ahi')/S
            U[r] += rest;
            V[r] = fmaf(rest, Ar[r] - sl.y, V[r]);    // rest*(Ahi'-logS)
        }
    }
    // fold per-thread Alo' factor: u = eb*rest, u*lnu = eb*(rest*(Ahi'-logS) + Alo'*rest)
    float vals[16];
#pragma unroll
    for (int r = 0; r < 8; ++r) {
        vals[r] = eb[r] * U[r];
        vals[8 + r] = eb[r] * fmaf(aterm[r], U[r], V[r]);
    }
#pragma unroll
    for (int m = 1; m < 64; m <<= 1)
#pragma unroll
        for (int q2 = 0; q2 < 16; ++q2)
            vals[q2] += __shfl_xor(vals[q2], m, 64);
    const int wv = tid >> 6, lane = tid & 63;
    if (lane == 0) {
#pragma unroll
        for (int q2 = 0; q2 < 16; ++q2) red[wv][q2] = vals[q2];
    }
    __syncthreads();
    if (tid < 16)
        red[0][tid] = red[0][tid] + red[1][tid] + red[2][tid] + red[3][tid];
    __syncthreads();
    if (tid < 8) {
        const float Uf = red[0][tid];
        const float Vf = red[0][8 + tid];
        atomicAdd(out, cs_s[tid] + Vf / Uf);
    }
}

extern "C" void kernel_launch(void* const* d_in, const int* in_sizes, int n_in,
                              void* d_out, int out_size, void* d_ws, size_t ws_size,
                              hipStream_t stream) {
    const float* x      = (const float*)d_in[0];
    const int*   y      = (const int*)d_in[1];
    const float* alpha0 = (const float*)d_in[2];
    const float* alpha  = (const float*)d_in[3];
    const float* beta0  = (const float*)d_in[4];
    const float* beta   = (const float*)d_in[5];

    float* le = (float*)d_ws;                                  // NB*NM floats
    float2* SL = (float2*)((char*)d_ws + ((NB * NM * 4 + 255) / 256) * 256);
    float* out = (float*)d_out;

    hipMemsetAsync(out, 0, sizeof(float), stream);
    hipMemsetAsync(le, 0, NB * NM * sizeof(float), stream);
    k1_le<<<512, 256, 0, stream>>>(x, alpha, le);
    k2_sl<<<256, 256, 0, stream>>>(beta, beta0, SL);
    k3_main<<<512, 256, 0, stream>>>(le, alpha0, y, beta, beta0, SL, out);
}

// Round 2
// 122.804 us; speedup vs baseline: 1.0794x; 1.0794x over previous
//
#include <hip/hip_runtime.h>
#include <math.h>

#define NB 4096
#define NF 2048
#define NM 14
#define NC 100
#define NK 16384

__device__ __forceinline__ float softplus_f(float v) {
    return fmaxf(v, 0.f) + log1pf(__expf(-fabsf(v)));
}

// K1: le_part[half][b][j] = x[b, half-of-F]·alpha[j, half-of-F]
// grid 512: blockIdx = (rowgroup<<1)|half ; 16 rows/block, 4 rows/wave, f-split x2
// No atomics: each (row, half) written by exactly one wave.
extern "C" __global__ void __launch_bounds__(256) k1_le(
        const float* __restrict__ x, const float* __restrict__ alpha,
        float* __restrict__ le_part) {
    const int tid = threadIdx.x;
    const int wave = tid >> 6, lane = tid & 63;
    const int grp = blockIdx.x >> 1;
    const int half = blockIdx.x & 1;
    const int row0 = grp * 16 + wave * 4;
    const float4* __restrict__ x4 = (const float4*)x;
    const float4* __restrict__ a4 = (const float4*)alpha;
    float acc[4][NM];
#pragma unroll
    for (int r = 0; r < 4; ++r)
#pragma unroll
        for (int j = 0; j < NM; ++j) acc[r][j] = 0.f;
#pragma unroll 1
    for (int cc = 0; cc < 4; ++cc) {
        const int f4i = half * 256 + cc * 64 + lane;
        float4 av[NM];
#pragma unroll
        for (int j = 0; j < NM; ++j) av[j] = a4[j * 512 + f4i];
#pragma unroll
        for (int r = 0; r < 4; ++r) {
            const float4 xv = x4[(row0 + r) * 512 + f4i];
#pragma unroll
            for (int j = 0; j < NM; ++j) {
                acc[r][j] = fmaf(xv.x, av[j].x, acc[r][j]);
                acc[r][j] = fmaf(xv.y, av[j].y, acc[r][j]);
                acc[r][j] = fmaf(xv.z, av[j].z, acc[r][j]);
                acc[r][j] = fmaf(xv.w, av[j].w, acc[r][j]);
            }
        }
    }
#pragma unroll
    for (int m = 1; m < 64; m <<= 1) {
#pragma unroll
        for (int r = 0; r < 4; ++r)
#pragma unroll
            for (int j = 0; j < NM; ++j)
                acc[r][j] += __shfl_xor(acc[r][j], m, 64);
    }
    if (lane == 0) {
        float* dst = le_part + half * (NB * NM) + row0 * NM;
#pragma unroll
        for (int r = 0; r < 4; ++r)
#pragma unroll
            for (int j = 0; j < NM; ++j)
                dst[r * NM + j] = acc[r][j];
    }
}

// K2: SL[k] = (1/S_k, log S_k), S_k = sum_c exp(beta0_c + beta_c·(2cb_k-1))
// grid 256 blocks: 64 k each, 4 class-quarters per k. |lp| <= ~13 so no max-sub needed.
extern "C" __global__ void __launch_bounds__(256) k2_sl(
        const float* __restrict__ beta, const float* __restrict__ beta0,
        float2* __restrict__ SL) {
    __shared__ float b2[NC * NM];
    __shared__ float base_s[NC];
    __shared__ float Sp[4][64];
    const int tid = threadIdx.x;
    for (int i = tid; i < NC * NM; i += 256) b2[i] = 2.f * beta[i];
    if (tid < NC) {
        float s = beta0[tid];
        for (int j = 0; j < NM; ++j) s -= beta[tid * NM + j];
        base_s[tid] = s;
    }
    __syncthreads();
    const int kl = tid & 63, q = tid >> 6;
    const int k = blockIdx.x * 64 + kl;
    float bits[NM];
#pragma unroll
    for (int j = 0; j < NM; ++j) bits[j] = (float)((k >> (13 - j)) & 1);
    float S = 0.f;
    for (int c = q * 25; c < q * 25 + 25; ++c) {
        float d = base_s[c];
#pragma unroll
        for (int j = 0; j < NM; ++j) d = fmaf(bits[j], b2[c * NM + j], d);
        S += __expf(d);
    }
    Sp[q][kl] = S;
    __syncthreads();
    if (tid < 64) {
        const float Sf = Sp[0][tid] + Sp[1][tid] + Sp[2][tid] + Sp[3][tid];
        SL[blockIdx.x * 64 + tid] = make_float2(1.f / Sf, __logf(Sf));
    }
}

// K3: per row b: U = sum_k exp(g-stab), V = sum_k exp(g-stab)*(g-stab)
//     f_b = cs_b + V/U,  cs_b = beta0_y - sum beta_y - spsum + stab
// grid 512 blocks x 256 thr, 8 rows/block; k = i*256 + tid, i=0..63.
// Writes one partial per block (no same-address atomic storm).
extern "C" __global__ void __launch_bounds__(256) k3_main(
        const float* __restrict__ le_part, const float* __restrict__ alpha0,
        const int* __restrict__ y, const float* __restrict__ beta,
        const float* __restrict__ beta0, const float2* __restrict__ SL,
        float* __restrict__ partial) {
    __shared__ float t_s[8][16];
    __shared__ float sp_s[8][16];
    __shared__ float cs_s[8];
    __shared__ float f_s[8];
    __shared__ float Alds[128][8];   // Ahi' = Ahi - UBhi (per h, per row)
    __shared__ float Elds[128][8];   // exp(Ahi')
    __shared__ float red[4][16];
    const int tid = threadIdx.x;
    const int b0 = blockIdx.x * 8;

    if (tid < 128) {
        const int r = tid >> 4, j = tid & 15;
        if (j < NM) {
            const int yv = y[b0 + r];
            const float lv = le_part[(b0 + r) * NM + j]
                           + le_part[NB * NM + (b0 + r) * NM + j] + alpha0[j];
            t_s[r][j] = lv + 2.f * beta[yv * NM + j];
            sp_s[r][j] = softplus_f(lv);
        }
    }
    __syncthreads();
    if (tid < 8) {
        const int yv = y[b0 + tid];
        float cs = beta0[yv];
        for (int j = 0; j < NM; ++j) {
            cs -= beta[yv * NM + j];
            cs += fmaxf(t_s[tid][j], 0.f) - sp_s[tid][j];  // stab - spsum
        }
        cs_s[tid] = cs;
    }
    // fill Ahi tables: 1024 entries = 128 h x 8 rows
#pragma unroll
    for (int e = 0; e < 4; ++e) {
        const int idx = tid + 256 * e;
        const int r = idx & 7, h = idx >> 3;
        float A = 0.f, ub = 0.f;
#pragma unroll
        for (int j = 0; j < 7; ++j) {
            const float tv = t_s[r][j];
            A += ((h >> (6 - j)) & 1) ? tv : 0.f;
            ub += fmaxf(tv, 0.f);
        }
        const float Ap = A - ub;
        Alds[h][r] = Ap;
        Elds[h][r] = __expf(Ap);
    }
    // per-thread Alo' and exp(Alo') per row (l = k & 127 = tid & 127)
    const int l = tid & 127;
    float eb[8], aterm[8];
#pragma unroll
    for (int r = 0; r < 8; ++r) {
        float A = 0.f, ub = 0.f;
#pragma unroll
        for (int j = 7; j < NM; ++j) {
            const float tv = t_s[r][j];
            A += ((l >> (13 - j)) & 1) ? tv : 0.f;
            ub += fmaxf(tv, 0.f);
        }
        aterm[r] = A - ub;
        eb[r] = __expf(A - ub);
    }
    __syncthreads();

    float U[8], V[8];
#pragma unroll
    for (int r = 0; r < 8; ++r) { U[r] = 0.f; V[r] = 0.f; }
    const int c = tid >> 7;   // wave-uniform
#pragma unroll 4
    for (int i = 0; i < 64; ++i) {
        const float2 sl = SL[i * 256 + tid];          // (1/S, logS) coalesced
        const int h = 2 * i + c;
        const float4 Aa = *(const float4*)&Alds[h][0];
        const float4 Ab = *(const float4*)&Alds[h][4];
        const float4 Ea = *(const float4*)&Elds[h][0];
        const float4 Eb = *(const float4*)&Elds[h][4];
        const float Ar[8] = {Aa.x, Aa.y, Aa.z, Aa.w, Ab.x, Ab.y, Ab.z, Ab.w};
        const float Er[8] = {Ea.x, Ea.y, Ea.z, Ea.w, Eb.x, Eb.y, Eb.z, Eb.w};
#pragma unroll
        for (int r = 0; r < 8; ++r) {
            const float rest = Er[r] * sl.x;          // exp(Ahi')/S
            U[r] += rest;
            V[r] = fmaf(rest, Ar[r] - sl.y, V[r]);    // rest*(Ahi'-logS)
        }
    }
    // fold per-thread Alo' factor: u = eb*rest, u*lnu = eb*(rest*(Ahi'-logS) + Alo'*rest)
    float vals[16];
#pragma unroll
    for (int r = 0; r < 8; ++r) {
        vals[r] = eb[r] * U[r];
        vals[8 + r] = eb[r] * fmaf(aterm[r], U[r], V[r]);
    }
#pragma unroll
    for (int m = 1; m < 64; m <<= 1)
#pragma unroll
        for (int q2 = 0; q2 < 16; ++q2)
            vals[q2] += __shfl_xor(vals[q2], m, 64);
    const int wv = tid >> 6, lane = tid & 63;
    if (lane == 0) {
#pragma unroll
        for (int q2 = 0; q2 < 16; ++q2) red[wv][q2] = vals[q2];
    }
    __syncthreads();
    if (tid < 16)
        red[0][tid] = red[0][tid] + red[1][tid] + red[2][tid] + red[3][tid];
    __syncthreads();
    if (tid < 8)
        f_s[tid] = cs_s[tid] + red[0][8 + tid] / red[0][tid];
    __syncthreads();
    if (tid == 0) {
        float s = 0.f;
#pragma unroll
        for (int r = 0; r < 8; ++r) s += f_s[r];
        partial[blockIdx.x] = s;
    }
}

// K4: reduce 512 block partials -> out (single block, full overwrite of d_out)
extern "C" __global__ void __launch_bounds__(256) k4_reduce(
        const float* __restrict__ partial, float* __restrict__ out) {
    __shared__ float red[4];
    const int tid = threadIdx.x;
    float s = partial[tid] + partial[tid + 256];
#pragma unroll
    for (int m = 1; m < 64; m <<= 1) s += __shfl_xor(s, m, 64);
    const int wv = tid >> 6, lane = tid & 63;
    if (lane == 0) red[wv] = s;
    __syncthreads();
    if (tid == 0) out[0] = red[0] + red[1] + red[2] + red[3];
}

extern "C" void kernel_launch(void* const* d_in, const int* in_sizes, int n_in,
                              void* d_out, int out_size, void* d_ws, size_t ws_size,
                              hipStream_t stream) {
    const float* x      = (const float*)d_in[0];
    const int*   y      = (const int*)d_in[1];
    const float* alpha0 = (const float*)d_in[2];
    const float* alpha  = (const float*)d_in[3];
    const float* beta0  = (const float*)d_in[4];
    const float* beta   = (const float*)d_in[5];

    char* ws = (char*)d_ws;
    float*  le_part = (float*)ws;                          // 2*NB*NM floats = 458752 B
    float2* SL      = (float2*)(ws + 2 * NB * NM * 4);     // 16384*8 B = 131072 B
    float*  partial = (float*)(ws + 2 * NB * NM * 4 + NK * 8); // 512 floats
    float*  out     = (float*)d_out;

    k1_le<<<512, 256, 0, stream>>>(x, alpha, le_part);
    k2_sl<<<256, 256, 0, stream>>>(beta, beta0, SL);
    k3_main<<<512, 256, 0, stream>>>(le_part, alpha0, y, beta, beta0, SL, partial);
    k4_reduce<<<1, 256, 0, stream>>>(partial, out);
}